// Round 4
// baseline (625.040 us; speedup 1.0000x reference)
//
#include <hip/hip_runtime.h>
#include <math.h>

#define B_    128
#define T_    24
#define NN    300
#define EE    9000
#define GG    (B_ * T_)      // 3072 graphs
#define GRUH  12
#define OUTF  1200
#define GT    16             // graphs per block tile
#define NGT   (GG / GT)      // 192 g-tiles

// ---------------------------------------------------------------------------
// Kernel 0: pack src|dst<<16 (topology shared by all graphs).
// ---------------------------------------------------------------------------
__global__ __launch_bounds__(256) void pack_edges(
    const int* __restrict__ src, const int* __restrict__ dst,
    unsigned int* __restrict__ pk)
{
    int e = blockIdx.x * 256 + threadIdx.x;
    if (e < EE) pk[e] = (unsigned int)src[e] | ((unsigned int)dst[e] << 16);
}

// ---------------------------------------------------------------------------
// Kernel 1: partial softmax accumulation, lane = graph-in-tile.
// Block = 16 graphs x 16-edge strips (wave = 4 g x 16 e, ew reads = 4 full
// 64B lines/instr). LDS den/num[n][2][17] (pad 17 -> atomic banks ~random,
// ~2/bank). This kills round-3's ~105-cyc random-scatter LDS instrs: all
// addressing is tile-regular. Chunked over edges (grid.y = C) -> tiny
// global partials P[c][gt][n][{den,num}][16].
// ---------------------------------------------------------------------------
__global__ __launch_bounds__(256, 2) void gat_partial(
    const float* __restrict__ x, const float* __restrict__ ew,
    const unsigned int* __restrict__ pk,
    const float* __restrict__ w_node, const float* __restrict__ w_edge,
    const float* __restrict__ attn_l, const float* __restrict__ attn_r,
    const float* __restrict__ attn_e,
    float* __restrict__ P, int chunkLen)
{
    __shared__ float xs[GT * NN];     // 19.2 KB   xs[g*300 + n]
    __shared__ float dn[NN * 34];     // 40.8 KB   dn[n*34 + a*17 + g]

    const int gt  = blockIdx.x;
    const int c   = blockIdx.y;
    const int tid = threadIdx.x;
    const int g0  = gt * GT;

    // stage x tile: 16 consecutive graph rows = contiguous 4800 floats
    for (int i = tid; i < GT * NN; i += 256) xs[i] = x[(size_t)g0 * NN + i];
    for (int i = tid; i < NN * 34; i += 256) dn[i] = 0.f;

    float cL = 0.f, cR = 0.f, cE = 0.f;
#pragma unroll
    for (int o = 0; o < 4; o++) {
        float wn = w_node[o];
        cL += wn * attn_l[o];
        cR += wn * attn_r[o];
        cE += w_edge[o] * attn_e[o];
    }
    __syncthreads();

    const int gl = tid >> 4;          // 0..15 graph lane
    const int el = tid & 15;          // 0..15 edge lane
    const int ebeg = c * chunkLen;
    const int eend = (ebeg + chunkLen < EE) ? ebeg + chunkLen : EE;

    const float* ewg = ew + (size_t)(g0 + gl) * EE;
    const float* xg  = xs + gl * NN;

#pragma unroll 4
    for (int e = ebeg + el; e < eend; e += 16) {
        float w = ewg[e];
        unsigned int p = pk[e];
        int si = (int)(p & 0xFFFFu);
        int di = (int)(p >> 16);
        float xsv = xg[si];
        float xdv = xg[di];
        float v = fmaf(cE, w, fmaf(cL, xsv, cR * xdv));
        v = fmaxf(v, 0.2f * v);                 // leaky relu
        float ex = __expf(v);
        unsafeAtomicAdd(&dn[di * 34 + gl], ex);
        unsafeAtomicAdd(&dn[di * 34 + 17 + gl], ex * xsv);
    }
    __syncthreads();

    // writeout: P[((c*NGT+gt)*300 + n)*32 + a*16 + g], fully coalesced
    float* Pb = P + (size_t)(c * NGT + gt) * NN * 32;
    for (int i = tid; i < NN * 32; i += 256) {
        int n = i >> 5, r = i & 31, a = r >> 4, g = r & 15;
        Pb[i] = dn[n * 34 + a * 17 + g];
    }
}

// ---------------------------------------------------------------------------
// Kernel 2: combine chunk partials -> S[g] = sum_n num_n/den_n.
// grid 48 x 256: 64 graphs/block, 4-way n-split per graph + LDS reduce.
// ---------------------------------------------------------------------------
__global__ __launch_bounds__(256) void combine_partials(
    const float* __restrict__ P, float* __restrict__ S, int C)
{
    __shared__ float red[256];
    const int tid = threadIdx.x;
    const int g   = blockIdx.x * 64 + (tid & 63);
    const int ns  = tid >> 6;               // 0..3 (n-range split)
    const int gt  = g >> 4, gl = g & 15;

    float acc = 0.f;
    for (int n = ns * 75; n < ns * 75 + 75; n++) {
        float d = 0.f, m = 0.f;
        for (int c = 0; c < C; c++) {
            const float* Pb = P + ((size_t)(c * NGT + gt) * NN + n) * 32;
            d += Pb[gl];
            m += Pb[16 + gl];
        }
        if (d > 0.f) acc += m / d;
    }
    red[tid] = acc;
    __syncthreads();
    if (tid < 64) S[g] = red[tid] + red[tid + 64] + red[tid + 128] + red[tid + 192];
}

// ---------------------------------------------------------------------------
// Fallback (ws too small for partials): round-3 per-graph kernel. Slow but
// correct; only used if ws_size < ~7.5 MB.
// ---------------------------------------------------------------------------
__global__ __launch_bounds__(256) void gat_pool_fb(
    const float* __restrict__ x, const float* __restrict__ ew,
    const unsigned int* __restrict__ pk,
    const float* __restrict__ w_node, const float* __restrict__ w_edge,
    const float* __restrict__ attn_l, const float* __restrict__ attn_r,
    const float* __restrict__ attn_e,
    float* __restrict__ S)
{
    __shared__ float xs[NN], den[NN], num[NN], red[4];
    const int g = blockIdx.x, tid = threadIdx.x;

    float cL = 0.f, cR = 0.f, cE = 0.f;
#pragma unroll
    for (int o = 0; o < 4; o++) {
        float wn = w_node[o];
        cL += wn * attn_l[o];
        cR += wn * attn_r[o];
        cE += w_edge[o] * attn_e[o];
    }
    const float* xrow = x + (size_t)g * NN;
    const float* erow = ew + (size_t)g * EE;
    for (int i = tid; i < NN; i += 256) { xs[i] = xrow[i]; den[i] = 0.f; num[i] = 0.f; }
    __syncthreads();
    for (int e = tid; e < EE; e += 256) {
        float w = erow[e];
        unsigned int p = pk[e];
        int si = (int)(p & 0xFFFFu), di = (int)(p >> 16);
        float xsv = xs[si];
        float v = fmaf(cE, w, fmaf(cL, xsv, cR * xs[di]));
        v = fmaxf(v, 0.2f * v);
        float ex = __expf(v);
        unsafeAtomicAdd(&den[di], ex);
        unsafeAtomicAdd(&num[di], ex * xsv);
    }
    __syncthreads();
    float acc = 0.f;
    for (int n = tid; n < NN; n += 256) { float d = den[n]; if (d > 0.f) acc += num[n] / d; }
    for (int off = 32; off > 0; off >>= 1) acc += __shfl_down(acc, off);
    if ((tid & 63) == 0) red[tid >> 6] = acc;
    __syncthreads();
    if (tid == 0) S[g] = red[0] + red[1] + red[2] + red[3];
}

// ---------------------------------------------------------------------------
// Kernel 3: GRU (24 steps, hidden 12) on wave 0 + FC (12 -> 1200).
// ---------------------------------------------------------------------------
__device__ __forceinline__ float sigmoidf_(float v) { return 1.0f / (1.0f + __expf(-v)); }

__global__ __launch_bounds__(256) void gru_fc(
    const float* __restrict__ S,
    const float* __restrict__ w_node, const float* __restrict__ gat_bias,
    const float* __restrict__ w_ih, const float* __restrict__ w_hh,
    const float* __restrict__ b_ih, const float* __restrict__ b_hh,
    const float* __restrict__ fc_w, const float* __restrict__ fc_b,
    float* __restrict__ out)
{
    __shared__ float Srow[T_];
    __shared__ float h[GRUH];
    __shared__ float gi_s[36], gh_s[36];

    const int b = blockIdx.x;
    const int tid = threadIdx.x;

    if (tid < T_) Srow[tid] = S[b * T_ + tid];
    if (tid < GRUH) h[tid] = 0.f;
    __syncthreads();

    if (tid < 64) {   // single wave: wave-lockstep LDS, no barriers
        const int lane = tid;
        float wn[4], gb[4];
#pragma unroll
        for (int i = 0; i < 4; i++) {
            wn[i] = w_node[i] * (1.0f / (float)NN);
            gb[i] = gat_bias[i];
        }
        float wih[4], whh[12], bih = 0.f, bhh = 0.f;
        if (lane < 36) {
#pragma unroll
            for (int i = 0; i < 4; i++)  wih[i] = w_ih[lane * 4 + i];
#pragma unroll
            for (int j = 0; j < 12; j++) whh[j] = w_hh[lane * 12 + j];
            bih = b_ih[lane];
            bhh = b_hh[lane];
        }
        for (int t = 0; t < T_; t++) {
            const float Sg = Srow[t];
            if (lane < 36) {
                float gi = bih, gh = bhh;
#pragma unroll
                for (int i = 0; i < 4; i++)  gi += (Sg * wn[i] + gb[i]) * wih[i];
#pragma unroll
                for (int j = 0; j < 12; j++) gh += h[j] * whh[j];
                gi_s[lane] = gi;
                gh_s[lane] = gh;
            }
            if (lane < GRUH) {
                float r = sigmoidf_(gi_s[lane] + gh_s[lane]);
                float z = sigmoidf_(gi_s[12 + lane] + gh_s[12 + lane]);
                float n = tanhf(gi_s[24 + lane] + r * gh_s[24 + lane]);
                h[lane] = (1.f - z) * n + z * h[lane];
            }
        }
    }
    __syncthreads();

    float hr[GRUH];
#pragma unroll
    for (int k = 0; k < GRUH; k++) hr[k] = h[k];

    for (int j = tid; j < OUTF; j += 256) {
        const float4* wr = (const float4*)(fc_w + j * GRUH);
        float4 w0 = wr[0], w1 = wr[1], w2 = wr[2];
        float o = fc_b[j];
        o += hr[0] * w0.x + hr[1] * w0.y + hr[2]  * w0.z + hr[3]  * w0.w;
        o += hr[4] * w1.x + hr[5] * w1.y + hr[6]  * w1.z + hr[7]  * w1.w;
        o += hr[8] * w2.x + hr[9] * w2.y + hr[10] * w2.z + hr[11] * w2.w;
        out[(size_t)b * OUTF + j] = o;
    }
}

// ---------------------------------------------------------------------------
extern "C" void kernel_launch(void* const* d_in, const int* in_sizes, int n_in,
                              void* d_out, int out_size, void* d_ws, size_t ws_size,
                              hipStream_t stream)
{
    const float* x        = (const float*)d_in[0];
    const float* ew       = (const float*)d_in[1];
    const int*   src      = (const int*)d_in[2];
    const int*   dst      = (const int*)d_in[3];
    const float* w_node   = (const float*)d_in[4];
    const float* w_edge   = (const float*)d_in[5];
    const float* attn_l   = (const float*)d_in[6];
    const float* attn_r   = (const float*)d_in[7];
    const float* attn_e   = (const float*)d_in[8];
    const float* gat_bias = (const float*)d_in[9];
    const float* w_ih     = (const float*)d_in[10];
    const float* w_hh     = (const float*)d_in[11];
    const float* b_ih     = (const float*)d_in[12];
    const float* b_hh     = (const float*)d_in[13];
    const float* fc_w     = (const float*)d_in[14];
    const float* fc_b     = (const float*)d_in[15];
    float* out = (float*)d_out;

    // ws layout: S[3072] | hbuf[1536] | pk[9000] | (pad) | P[C * 192*300*32]
    char* ws = (char*)d_ws;
    float*        S  = (float*)ws;                        // 12288 B
    unsigned int* pk = (unsigned int*)(ws + 18432);       // 36000 B
    float*        P  = (float*)(ws + 65536);
    const size_t  pBytes = (size_t)NGT * NN * 32 * sizeof(float);  // 7.37 MB per chunk

    int C = 0;
    if      (ws_size >= 65536 + 3 * pBytes) C = 3;
    else if (ws_size >= 65536 + 2 * pBytes) C = 2;
    else if (ws_size >= 65536 + 1 * pBytes) C = 1;

    pack_edges<<<(EE + 255) / 256, 256, 0, stream>>>(src, dst, pk);

    if (C > 0) {
        int chunkLen = (EE + C - 1) / C;
        gat_partial<<<dim3(NGT, C), 256, 0, stream>>>(
            x, ew, pk, w_node, w_edge, attn_l, attn_r, attn_e, P, chunkLen);
        combine_partials<<<GG / 64, 256, 0, stream>>>(P, S, C);
    } else {
        gat_pool_fb<<<GG, 256, 0, stream>>>(
            x, ew, pk, w_node, w_edge, attn_l, attn_r, attn_e, S);
    }

    gru_fc<<<B_, 256, 0, stream>>>(S, w_node, gat_bias, w_ih, w_hh,
                                   b_ih, b_hh, fc_w, fc_b, out);
}